// Round 2
// baseline (541.537 us; speedup 1.0000x reference)
//
#include <hip/hip_runtime.h>

#define NB 256      // batch
#define TT 200      // time steps
#define DD 1250     // input dim
#define H1 100
#define H2 20
#define NO 2

#define KC 50       // K-chunk
#define NCHUNK 25   // 1250 / 50
#define WP 104      // w_s row pitch (dwords)

__launch_bounds__(1024, 4)
__global__ void rnn_fused(const float* __restrict__ x,
                          const float* __restrict__ Wih1,
                          const float* __restrict__ Whh1,
                          const float* __restrict__ bih1,
                          const float* __restrict__ bhh1,
                          const float* __restrict__ Wih2,
                          const float* __restrict__ Whh2,
                          const float* __restrict__ bih2,
                          const float* __restrict__ bhh2,
                          const float* __restrict__ Wfc,
                          const float* __restrict__ bfc,
                          const float* __restrict__ mask1,
                          const float* __restrict__ mask2,
                          float* __restrict__ out)
{
    __shared__ alignas(16) float pre1_s[TT * H1];   // 80000 B
    __shared__ alignas(16) float x_s[TT * KC];      // 40000 B
    __shared__ alignas(16) float w_s[KC * WP];      // 20800 B
    __shared__ alignas(16) float h1_s[2][H1];
    __shared__ alignas(16) float o1_s[2][H1];
    __shared__ alignas(16) float h2_s[2][H2];
    __shared__ alignas(16) float h2f_s[H2];

    const int tid = threadIdx.x;
    const int b   = blockIdx.x;
    const float* xb  = x     + (size_t)b * TT * DD;
    const float* m1b = mask1 + (size_t)b * TT * H1;

    // ================= Phase 1: pre1 = x[b] @ W_ih1^T (fp32, in-LDS) =========
    // 1000 active threads: hg=tid%25 -> 4 h-cols, tg=tid/25 -> 5 t-rows.
    const int hg = tid % 25;
    const int tg = tid / 25;
    const bool act = (tg < 40);
    const int t0 = tg * 5;

    float acc[5][4];
    #pragma unroll
    for (int r = 0; r < 5; ++r)
        #pragma unroll
        for (int c = 0; c < 4; ++c) acc[r][c] = 0.f;

    // register-double-buffered staging (issue-early / write-late)
    float xr[10], wr[5];
    #pragma unroll
    for (int q = 0; q < 10; ++q) {
        int idx = tid + q * 1024;
        if (idx < TT * KC) xr[q] = xb[(idx / KC) * DD + (idx % KC)];
    }
    #pragma unroll
    for (int q = 0; q < 5; ++q) {
        int idx = tid + q * 1024;
        if (idx < H1 * KC) wr[q] = Wih1[(idx / KC) * DD + (idx % KC)];
    }

    for (int kc = 0; kc < NCHUNK; ++kc) {
        #pragma unroll
        for (int q = 0; q < 10; ++q) {
            int idx = tid + q * 1024;
            if (idx < TT * KC) x_s[idx] = xr[q];                 // [t][KC]
        }
        #pragma unroll
        for (int q = 0; q < 5; ++q) {
            int idx = tid + q * 1024;
            if (idx < H1 * KC) w_s[(idx % KC) * WP + (idx / KC)] = wr[q];
        }
        __syncthreads();

        if (kc + 1 < NCHUNK) {                // prefetch next chunk
            const int kb = (kc + 1) * KC;
            #pragma unroll
            for (int q = 0; q < 10; ++q) {
                int idx = tid + q * 1024;
                if (idx < TT * KC) xr[q] = xb[(idx / KC) * DD + kb + (idx % KC)];
            }
            #pragma unroll
            for (int q = 0; q < 5; ++q) {
                int idx = tid + q * 1024;
                if (idx < H1 * KC) wr[q] = Wih1[(idx / KC) * DD + kb + (idx % KC)];
            }
        }

        if (act) {
            #pragma unroll 5
            for (int kk = 0; kk < KC; ++kk) {
                const float4 wv = *(const float4*)&w_s[kk * WP + 4 * hg];
                #pragma unroll
                for (int r = 0; r < 5; ++r) {
                    const float xv = x_s[(t0 + r) * KC + kk];    // broadcast
                    acc[r][0] = fmaf(xv, wv.x, acc[r][0]);
                    acc[r][1] = fmaf(xv, wv.y, acc[r][1]);
                    acc[r][2] = fmaf(xv, wv.z, acc[r][2]);
                    acc[r][3] = fmaf(xv, wv.w, acc[r][3]);
                }
            }
        }
        __syncthreads();
    }

    if (act) {
        #pragma unroll
        for (int r = 0; r < 5; ++r) {
            float4 v = make_float4(acc[r][0], acc[r][1], acc[r][2], acc[r][3]);
            *(float4*)&pre1_s[(t0 + r) * H1 + 4 * hg] = v;
        }
    }

    // ============== per-thread scan weights into registers ===================
    // layer1: threads 0..199, h = tid>>1, p = tid&1 -> 50-elem half-dot each
    const int h = tid >> 1;
    const int p = tid & 1;
    const bool l1t = (tid < 200);
    float w1r[50];
    float b1 = 0.f;
    if (l1t) {
        #pragma unroll
        for (int jq = 0; jq < 25; ++jq) {
            float2 v = *(const float2*)&Whh1[h * H1 + p * 50 + 2 * jq];
            w1r[2 * jq] = v.x; w1r[2 * jq + 1] = v.y;
        }
        if (p == 0) b1 = bih1[h] + bhh1[h];
    }
    // layer2: threads 256..335, k2 = (tid-256)>>2, p2 = (tid-256)&3
    const bool l2t = (tid >= 256 && tid < 256 + 4 * H2);
    const int k2 = (tid - 256) >> 2;
    const int p2 = (tid - 256) & 3;
    float wi2r[25], wh2r[5];
    float b2 = 0.f;
    if (l2t) {
        #pragma unroll
        for (int j = 0; j < 25; ++j) wi2r[j] = Wih2[k2 * H1 + p2 * 25 + j];
        #pragma unroll
        for (int l = 0; l < 5; ++l)  wh2r[l] = Whh2[k2 * H2 + p2 * 5 + l];
        if (p2 == 0) b2 = bih2[k2] + bhh2[k2];
    }

    if (tid < H1) { h1_s[0][tid] = 0.f; h1_s[1][tid] = 0.f;
                    o1_s[0][tid] = 0.f; o1_s[1][tid] = 0.f; }
    if (tid < H2) { h2_s[0][tid] = 0.f; h2_s[1][tid] = 0.f; }

    // 4-deep prefetch pipelines: mask1 (global) on p==1, pre1 (LDS) on p==0
    const bool pm = l1t && (p == 1);
    const bool pp = l1t && (p == 0);
    float mreg[4], preg[4];
    #pragma unroll
    for (int u = 0; u < 4; ++u) {
        if (pm) mreg[u] = m1b[u * H1 + h];
        if (pp) preg[u] = pre1_s[u * H1 + h];
    }
    __syncthreads();

    // ================= Phase 2: fused two-layer scan =========================
    for (int tb = 0; tb < TT; tb += 4) {
        #pragma unroll
        for (int u = 0; u < 4; ++u) {
            const int t = tb + u;
            const int cur = t & 1, nxt = cur ^ 1;

            if (l1t) {
                float a0 = pp ? (preg[u] + b1) : 0.f;
                float a1 = 0.f, a2 = 0.f, a3 = 0.f;
                const float* hb = &h1_s[cur][p * 50];
                #pragma unroll
                for (int jq = 0; jq < 12; ++jq) {
                    const float4 hv = *(const float4*)&hb[4 * jq];
                    a0 = fmaf(w1r[4 * jq + 0], hv.x, a0);
                    a1 = fmaf(w1r[4 * jq + 1], hv.y, a1);
                    a2 = fmaf(w1r[4 * jq + 2], hv.z, a2);
                    a3 = fmaf(w1r[4 * jq + 3], hv.w, a3);
                }
                const float2 ht = *(const float2*)&hb[48];
                a0 = fmaf(w1r[48], ht.x, a0);
                a1 = fmaf(w1r[49], ht.y, a1);
                float part = (a0 + a1) + (a2 + a3);
                float tot  = part + __shfl_xor(part, 1);
                tot = fmaxf(tot, 0.f);                       // h1(t)
                if (p == 0) h1_s[nxt][h] = tot;
                else        o1_s[nxt][h] = tot * mreg[u];
            }

            if (l2t && t >= 1) {
                float a0 = (p2 == 0) ? b2 : 0.f;
                float a1 = 0.f, a2 = 0.f, a3 = 0.f;
                const float* ob = &o1_s[cur][p2 * 25];
                #pragma unroll
                for (int iq = 0; iq < 6; ++iq) {
                    const float4 ov = *(const float4*)&ob[4 * iq];
                    a0 = fmaf(wi2r[4 * iq + 0], ov.x, a0);
                    a1 = fmaf(wi2r[4 * iq + 1], ov.y, a1);
                    a2 = fmaf(wi2r[4 * iq + 2], ov.z, a2);
                    a3 = fmaf(wi2r[4 * iq + 3], ov.w, a3);
                }
                a0 = fmaf(wi2r[24], ob[24], a0);
                const float* gb = &h2_s[cur][p2 * 5];
                #pragma unroll
                for (int l = 0; l < 5; ++l) a0 = fmaf(wh2r[l], gb[l], a0);
                float part = (a0 + a1) + (a2 + a3);
                part += __shfl_xor(part, 1);
                part += __shfl_xor(part, 2);
                const float h2v = fmaxf(part, 0.f);          // h2(t-1)
                if (p2 == 0) h2_s[nxt][k2] = h2v;
            }

            if (t + 4 < TT) {                                // refill pipelines
                if (pm) mreg[u] = m1b[(t + 4) * H1 + h];
                if (pp) preg[u] = pre1_s[(t + 4) * H1 + h];
            }
            __syncthreads();
        }
    }

    // epilogue iteration t = TT: layer2 computes h2(199)
    {
        const int cur = TT & 1;                              // 0
        if (l2t) {
            float a0 = (p2 == 0) ? b2 : 0.f;
            float a1 = 0.f, a2 = 0.f, a3 = 0.f;
            const float* ob = &o1_s[cur][p2 * 25];
            #pragma unroll
            for (int iq = 0; iq < 6; ++iq) {
                const float4 ov = *(const float4*)&ob[4 * iq];
                a0 = fmaf(wi2r[4 * iq + 0], ov.x, a0);
                a1 = fmaf(wi2r[4 * iq + 1], ov.y, a1);
                a2 = fmaf(wi2r[4 * iq + 2], ov.z, a2);
                a3 = fmaf(wi2r[4 * iq + 3], ov.w, a3);
            }
            a0 = fmaf(wi2r[24], ob[24], a0);
            const float* gb = &h2_s[cur][p2 * 5];
            #pragma unroll
            for (int l = 0; l < 5; ++l) a0 = fmaf(wh2r[l], gb[l], a0);
            float part = (a0 + a1) + (a2 + a3);
            part += __shfl_xor(part, 1);
            part += __shfl_xor(part, 2);
            if (p2 == 0) h2f_s[k2] = fmaxf(part, 0.f);       // h2(199)
        }
        __syncthreads();
    }

    // ================= FC on last step ======================================
    if (tid < NO) {
        const float* m2 = mask2 + ((size_t)b * TT + (TT - 1)) * H2;
        float s = bfc[tid];
        #pragma unroll
        for (int k = 0; k < H2; ++k)
            s = fmaf(Wfc[tid * H2 + k], h2f_s[k] * m2[k], s);
        out[b * NO + tid] = s;
    }
}

extern "C" void kernel_launch(void* const* d_in, const int* in_sizes, int n_in,
                              void* d_out, int out_size, void* d_ws, size_t ws_size,
                              hipStream_t stream) {
    rnn_fused<<<dim3(NB), dim3(1024), 0, stream>>>(
        (const float*)d_in[0],  (const float*)d_in[1],  (const float*)d_in[2],
        (const float*)d_in[3],  (const float*)d_in[4],  (const float*)d_in[5],
        (const float*)d_in[6],  (const float*)d_in[7],  (const float*)d_in[8],
        (const float*)d_in[9],  (const float*)d_in[10], (const float*)d_in[11],
        (const float*)d_in[12], (float*)d_out);
}

// Round 3
// 377.966 us; speedup vs baseline: 1.4328x; 1.4328x over previous
//
#include <hip/hip_runtime.h>

#define NB 256      // batch
#define TT 200      // time steps
#define DD 1250     // input dim
#define H1 100
#define H2 20
#define NO 2

#define KCH 256     // K-chunk for phase-1 MFMA (K padded to 1280)
#define NCH 5       // 1280 / 256
#define WROWS 112   // 100 h-rows + 12 zero-pad rows (7 n-tiles of 16)
#define WPIT 264    // shorts per w_s row: 256 + 8 pad -> stride = 4 banks (2-way, free)

typedef __attribute__((ext_vector_type(4))) float f32x4;
typedef __attribute__((ext_vector_type(8))) short s16x8;

__device__ __forceinline__ unsigned short f2bf(float f) {
    unsigned u = __builtin_bit_cast(unsigned, f);
    u += 0x7FFFu + ((u >> 16) & 1u);          // round-to-nearest-even
    return (unsigned short)(u >> 16);
}

struct P2 {                                    // phase-2 LDS view
    float pre1[TT * H1];                       // 80000 B
    float h1[2][H1];
    float o1[2][H1];
    float h2[2][H2];
    float h2f[H2];
};
#define P1BYTES (WROWS * WPIT * 2)
#define SMEMBYTES (sizeof(P2) > (size_t)P1BYTES ? sizeof(P2) : (size_t)P1BYTES)

__launch_bounds__(1024, 2)                     // 2 waves/EU min -> 128 VGPR, no spills
__global__ void rnn_fused(const float* __restrict__ x,
                          const float* __restrict__ Wih1,
                          const float* __restrict__ Whh1,
                          const float* __restrict__ bih1,
                          const float* __restrict__ bhh1,
                          const float* __restrict__ Wih2,
                          const float* __restrict__ Whh2,
                          const float* __restrict__ bih2,
                          const float* __restrict__ bhh2,
                          const float* __restrict__ Wfc,
                          const float* __restrict__ bfc,
                          const float* __restrict__ mask1,
                          const float* __restrict__ mask2,
                          float* __restrict__ out)
{
    __shared__ __align__(16) char smem[SMEMBYTES];
    unsigned short* w_s = (unsigned short*)smem;   // phase 1: bf16 W chunk
    P2* sp = (P2*)smem;                            // phase 2 (aliases w_s; sequenced)

    const int tid = threadIdx.x;
    const int b   = blockIdx.x;
    const float* xb  = x     + (size_t)b * TT * DD;
    const float* m1b = mask1 + (size_t)b * TT * H1;

    // ======== Phase 1: pre1[200][100] = x[b] @ Wih1^T via bf16 MFMA ==========
    // 13 MFMA waves; wave wv owns rows [wv*16, wv*16+16). A-frags come straight
    // from global (fp32->bf16 in reg); only W staged in LDS (L3-hot, shared).
    const int wv  = tid >> 6;
    const int ln  = tid & 63;
    const bool mfw = (wv < 13);
    const int c16 = ln & 15;                   // A: row-in-tile / B: col (=h)
    const int kg  = (ln >> 4) << 3;            // k sub-offset {0,8,16,24}
    const int arow = (wv * 16 + c16 < TT) ? (wv * 16 + c16) : (TT - 1);
    const float* xrow = xb + (size_t)arow * DD;

    f32x4 acc[7];
    #pragma unroll
    for (int i = 0; i < 7; ++i)
        #pragma unroll
        for (int c = 0; c < 4; ++c) acc[i][c] = 0.f;

    // zero the pad rows h=100..111 once (never overwritten by staging)
    for (int i = tid; i < (WROWS - H1) * WPIT; i += 1024)
        w_s[H1 * WPIT + i] = 0;

    float4 xqa[3], xqb[3];                     // 3-deep kstep prefetch ring

    for (int kc = 0; kc < NCH; ++kc) {
        const int k0 = kc * KCH;
        __syncthreads();                       // prev chunk's w_s fully consumed

        // ---- stage Wih1 chunk (100 x 256 fp32 -> bf16), coalesced by row ----
        #pragma unroll
        for (int q = 0; q < 7; ++q) {
            const int vi = tid + q * 1024;
            if (vi < H1 * (KCH / 4)) {
                const int hh = vi >> 6;            // w-row
                const int kk = (vi & 63) << 2;     // k within chunk
                const int gk = k0 + kk;
                float4 wv4;
                if (gk + 3 < DD) {
                    wv4 = *(const float4*)&Wih1[(size_t)hh * DD + gk];
                } else {
                    wv4.x = (gk + 0 < DD) ? Wih1[(size_t)hh * DD + gk + 0] : 0.f;
                    wv4.y = (gk + 1 < DD) ? Wih1[(size_t)hh * DD + gk + 1] : 0.f;
                    wv4.z = (gk + 2 < DD) ? Wih1[(size_t)hh * DD + gk + 2] : 0.f;
                    wv4.w = (gk + 3 < DD) ? Wih1[(size_t)hh * DD + gk + 3] : 0.f;
                }
                const unsigned lo = (unsigned)f2bf(wv4.x) | ((unsigned)f2bf(wv4.y) << 16);
                const unsigned hi = (unsigned)f2bf(wv4.z) | ((unsigned)f2bf(wv4.w) << 16);
                *(uint2*)&w_s[hh * WPIT + kk] = make_uint2(lo, hi);
            }
        }
        __syncthreads();                       // w_s ready

        if (mfw) {
            auto xissue = [&](int s, float4& da, float4& db) {
                const int gk = k0 + s * 32 + kg;
                if (gk + 7 < DD) {             // fast path (all but tail chunk)
                    da = *(const float4*)&xrow[gk];
                    db = *(const float4*)&xrow[gk + 4];
                } else {                       // guarded tail (k >= 1250 -> 0)
                    float tv[8];
                    #pragma unroll
                    for (int e = 0; e < 8; ++e)
                        tv[e] = (gk + e < DD) ? xrow[gk + e] : 0.f;
                    da = make_float4(tv[0], tv[1], tv[2], tv[3]);
                    db = make_float4(tv[4], tv[5], tv[6], tv[7]);
                }
            };
            xissue(0, xqa[0], xqb[0]);
            xissue(1, xqa[1], xqb[1]);
            xissue(2, xqa[2], xqb[2]);
            #pragma unroll
            for (int s = 0; s < 8; ++s) {      // 8 k-steps of 32
                const int sl = s % 3;          // compile-time under unroll
                const float4 ua = xqa[sl], ub = xqb[sl];
                if (s + 3 < 8) xissue(s + 3, xqa[(s + 3) % 3], xqb[(s + 3) % 3]);
                const s16x8 af = {
                    (short)f2bf(ua.x), (short)f2bf(ua.y),
                    (short)f2bf(ua.z), (short)f2bf(ua.w),
                    (short)f2bf(ub.x), (short)f2bf(ub.y),
                    (short)f2bf(ub.z), (short)f2bf(ub.w) };
                #pragma unroll
                for (int nt = 0; nt < 7; ++nt) {
                    const s16x8 bf = *(const s16x8*)
                        &w_s[(nt * 16 + c16) * WPIT + s * 32 + kg];
                    acc[nt] = __builtin_amdgcn_mfma_f32_16x16x32_bf16(
                        af, bf, acc[nt], 0, 0, 0);
                }
            }
        }
    }

    __syncthreads();                           // all MFMA done; w_s now dead

    // C/D layout (m89-verified): col = l&15, row = (l>>4)*4 + reg
    if (mfw) {
        const int srow = wv * 16 + ((ln >> 4) << 2);
        #pragma unroll
        for (int nt = 0; nt < 7; ++nt) {
            const int col = nt * 16 + c16;
            if (col < H1) {
                #pragma unroll
                for (int r = 0; r < 4; ++r) {
                    const int row = srow + r;
                    if (row < TT) sp->pre1[row * H1 + col] = acc[nt][r];
                }
            }
        }
    }

    // ============== per-thread scan weights into registers ===================
    const int h = tid >> 1;
    const int p = tid & 1;
    const bool l1t = (tid < 200);
    float w1r[50]; float b1 = 0.f;
    if (l1t) {
        #pragma unroll
        for (int jq = 0; jq < 25; ++jq) {
            float2 v = *(const float2*)&Whh1[h * H1 + p * 50 + 2 * jq];
            w1r[2 * jq] = v.x; w1r[2 * jq + 1] = v.y;
        }
        if (p == 0) b1 = bih1[h] + bhh1[h];
    }
    const bool l2t = (tid >= 256 && tid < 256 + 4 * H2);
    const int k2 = (tid - 256) >> 2;
    const int p2 = (tid - 256) & 3;
    float wi2r[25], wh2r[5]; float b2 = 0.f;
    if (l2t) {
        #pragma unroll
        for (int j = 0; j < 25; ++j) wi2r[j] = Wih2[k2 * H1 + p2 * 25 + j];
        #pragma unroll
        for (int l = 0; l < 5; ++l)  wh2r[l] = Whh2[k2 * H2 + p2 * 5 + l];
        if (p2 == 0) b2 = bih2[k2] + bhh2[k2];
    }
    if (tid < H1) { sp->h1[0][tid] = 0.f; sp->h1[1][tid] = 0.f;
                    sp->o1[0][tid] = 0.f; sp->o1[1][tid] = 0.f; }
    if (tid < H2) { sp->h2[0][tid] = 0.f; sp->h2[1][tid] = 0.f; }

    const bool pm = l1t && (p == 1);
    const bool pp = l1t && (p == 0);
    float mreg[4], preg[4];
    #pragma unroll
    for (int u = 0; u < 4; ++u) if (pm) mreg[u] = m1b[u * H1 + h];

    __syncthreads();                           // pre1 + zeroed states visible

    #pragma unroll
    for (int u = 0; u < 4; ++u) if (pp) preg[u] = sp->pre1[u * H1 + h];

    // ================= Phase 2: fused two-layer scan =========================
    for (int tb = 0; tb < TT; tb += 4) {
        #pragma unroll
        for (int u = 0; u < 4; ++u) {
            const int t = tb + u;
            const int cur = t & 1, nxt = cur ^ 1;

            if (l1t) {
                float a0 = pp ? (preg[u] + b1) : 0.f;
                float a1 = 0.f, a2 = 0.f, a3 = 0.f;
                const float* hb = &sp->h1[cur][p * 50];
                #pragma unroll
                for (int jq = 0; jq < 12; ++jq) {
                    const float4 hv = *(const float4*)&hb[4 * jq];
                    a0 = fmaf(w1r[4 * jq + 0], hv.x, a0);
                    a1 = fmaf(w1r[4 * jq + 1], hv.y, a1);
                    a2 = fmaf(w1r[4 * jq + 2], hv.z, a2);
                    a3 = fmaf(w1r[4 * jq + 3], hv.w, a3);
                }
                const float2 ht = *(const float2*)&hb[48];
                a0 = fmaf(w1r[48], ht.x, a0);
                a1 = fmaf(w1r[49], ht.y, a1);
                float part = (a0 + a1) + (a2 + a3);
                float tot  = part + __shfl_xor(part, 1);
                tot = fmaxf(tot, 0.f);                       // h1(t)
                if (p == 0) sp->h1[nxt][h] = tot;
                else        sp->o1[nxt][h] = tot * mreg[u];
            }

            if (l2t && t >= 1) {
                float a0 = (p2 == 0) ? b2 : 0.f;
                float a1 = 0.f, a2 = 0.f, a3 = 0.f;
                const float* ob = &sp->o1[cur][p2 * 25];
                #pragma unroll
                for (int iq = 0; iq < 6; ++iq) {
                    const float4 ov = *(const float4*)&ob[4 * iq];
                    a0 = fmaf(wi2r[4 * iq + 0], ov.x, a0);
                    a1 = fmaf(wi2r[4 * iq + 1], ov.y, a1);
                    a2 = fmaf(wi2r[4 * iq + 2], ov.z, a2);
                    a3 = fmaf(wi2r[4 * iq + 3], ov.w, a3);
                }
                a0 = fmaf(wi2r[24], ob[24], a0);
                const float* gb = &sp->h2[cur][p2 * 5];
                #pragma unroll
                for (int l = 0; l < 5; ++l) a0 = fmaf(wh2r[l], gb[l], a0);
                float part = (a0 + a1) + (a2 + a3);
                part += __shfl_xor(part, 1);
                part += __shfl_xor(part, 2);
                const float h2v = fmaxf(part, 0.f);          // h2(t-1)
                if (p2 == 0) sp->h2[nxt][k2] = h2v;
            }

            if (t + 4 < TT) {
                if (pm) mreg[u] = m1b[(t + 4) * H1 + h];
                if (pp) preg[u] = sp->pre1[(t + 4) * H1 + h];
            }
            __syncthreads();
        }
    }

    // epilogue t = TT: layer2 computes h2(199)
    {
        const int cur = TT & 1;                              // 0
        if (l2t) {
            float a0 = (p2 == 0) ? b2 : 0.f;
            float a1 = 0.f, a2 = 0.f, a3 = 0.f;
            const float* ob = &sp->o1[cur][p2 * 25];
            #pragma unroll
            for (int iq = 0; iq < 6; ++iq) {
                const float4 ov = *(const float4*)&ob[4 * iq];
                a0 = fmaf(wi2r[4 * iq + 0], ov.x, a0);
                a1 = fmaf(wi2r[4 * iq + 1], ov.y, a1);
                a2 = fmaf(wi2r[4 * iq + 2], ov.z, a2);
                a3 = fmaf(wi2r[4 * iq + 3], ov.w, a3);
            }
            a0 = fmaf(wi2r[24], ob[24], a0);
            const float* gb = &sp->h2[cur][p2 * 5];
            #pragma unroll
            for (int l = 0; l < 5; ++l) a0 = fmaf(wh2r[l], gb[l], a0);
            float part = (a0 + a1) + (a2 + a3);
            part += __shfl_xor(part, 1);
            part += __shfl_xor(part, 2);
            if (p2 == 0) sp->h2f[k2] = fmaxf(part, 0.f);     // h2(199)
        }
        __syncthreads();
    }

    // ================= FC on last step ======================================
    if (tid < NO) {
        const float* m2 = mask2 + ((size_t)b * TT + (TT - 1)) * H2;
        float s = bfc[tid];
        #pragma unroll
        for (int k = 0; k < H2; ++k)
            s = fmaf(Wfc[tid * H2 + k], sp->h2f[k] * m2[k], s);
        out[b * NO + tid] = s;
    }
}

extern "C" void kernel_launch(void* const* d_in, const int* in_sizes, int n_in,
                              void* d_out, int out_size, void* d_ws, size_t ws_size,
                              hipStream_t stream) {
    rnn_fused<<<dim3(NB), dim3(1024), 0, stream>>>(
        (const float*)d_in[0],  (const float*)d_in[1],  (const float*)d_in[2],
        (const float*)d_in[3],  (const float*)d_in[4],  (const float*)d_in[5],
        (const float*)d_in[6],  (const float*)d_in[7],  (const float*)d_in[8],
        (const float*)d_in[9],  (const float*)d_in[10], (const float*)d_in[11],
        (const float*)d_in[12], (float*)d_out);
}

// Round 4
// 376.858 us; speedup vs baseline: 1.4370x; 1.0029x over previous
//
#include <hip/hip_runtime.h>

#define NB 256      // batch
#define TT 200      // time steps
#define DD 1250     // input dim
#define H1 100
#define H2 20
#define NO 2

#define KCH 256     // K-chunk for phase-1 MFMA (K padded to 1280)
#define NCH 5       // 1280 / 256
#define WROWS 112   // 100 h-rows + 12 zero-pad rows (7 n-tiles of 16)
#define WPIT 264    // shorts per w_s row: 256 + 8 pad

typedef __attribute__((ext_vector_type(4))) float f32x4;
typedef __attribute__((ext_vector_type(8))) short s16x8;

__device__ __forceinline__ unsigned short f2bf(float f) {
    unsigned u = __builtin_bit_cast(unsigned, f);
    u += 0x7FFFu + ((u >> 16) & 1u);          // round-to-nearest-even
    return (unsigned short)(u >> 16);
}

struct P2 {                                    // phase-2 LDS view
    float pre1[TT * H1];                       // 80000 B
    float h1[2][H1];
    float o1[2][H1];
    float h2[2][H2];
    float h2f[H2];
};
#define P1BYTES (WROWS * WPIT * 2)
#define SMEMBYTES (sizeof(P2) > (size_t)P1BYTES ? sizeof(P2) : (size_t)P1BYTES)

// LDS=82KB already caps at 1 block/CU; declare exactly that so the compiler
// gets the full 128-VGPR/wave budget (second arg acts as min BLOCKS/CU here:
// (1024,2) and (1024,4) both produced a 64-VGPR cap + scratch spills).
__launch_bounds__(1024, 1)
__global__ void rnn_fused(const float* __restrict__ x,
                          const float* __restrict__ Wih1,
                          const float* __restrict__ Whh1,
                          const float* __restrict__ bih1,
                          const float* __restrict__ bhh1,
                          const float* __restrict__ Wih2,
                          const float* __restrict__ Whh2,
                          const float* __restrict__ bih2,
                          const float* __restrict__ bhh2,
                          const float* __restrict__ Wfc,
                          const float* __restrict__ bfc,
                          const float* __restrict__ mask1,
                          const float* __restrict__ mask2,
                          float* __restrict__ out)
{
    __shared__ __align__(16) char smem[SMEMBYTES];
    unsigned short* w_s = (unsigned short*)smem;   // phase 1: bf16 W chunk
    P2* sp = (P2*)smem;                            // phase 2 (aliases w_s; sequenced)

    const int tid = threadIdx.x;
    const int b   = blockIdx.x;
    const float* xb  = x     + (size_t)b * TT * DD;
    const float* m1b = mask1 + (size_t)b * TT * H1;

    // ======== Phase 1: pre1[200][100] = x[b] @ Wih1^T via bf16 MFMA ==========
    const int wv  = tid >> 6;
    const int ln  = tid & 63;
    const bool mfw = (wv < 13);
    const int c16 = ln & 15;                   // A: row-in-tile / B: col (=h)
    const int kg  = (ln >> 4) << 3;            // k sub-offset {0,8,16,24}
    const int arow = (wv * 16 + c16 < TT) ? (wv * 16 + c16) : (TT - 1);
    const float* xrow = xb + (size_t)arow * DD;

    f32x4 acc[7];
    #pragma unroll
    for (int i = 0; i < 7; ++i)
        #pragma unroll
        for (int c = 0; c < 4; ++c) acc[i][c] = 0.f;

    // zero the pad rows h=100..111 once
    for (int i = tid; i < (WROWS - H1) * WPIT; i += 1024)
        w_s[H1 * WPIT + i] = 0;

    float4 xqa[2], xqb[2];                     // 2-deep kstep prefetch ring

    for (int kc = 0; kc < NCH; ++kc) {
        const int k0 = kc * KCH;
        __syncthreads();                       // prev chunk's w_s fully consumed

        // ---- stage Wih1 chunk (100 x 256 fp32 -> bf16), coalesced by row ----
        #pragma unroll
        for (int q = 0; q < 7; ++q) {
            const int vi = tid + q * 1024;
            if (vi < H1 * (KCH / 4)) {
                const int hh = vi >> 6;            // w-row
                const int kk = (vi & 63) << 2;     // k within chunk
                const int gk = k0 + kk;
                float4 wv4;
                if (gk + 3 < DD) {
                    wv4 = *(const float4*)&Wih1[(size_t)hh * DD + gk];
                } else {
                    wv4.x = (gk + 0 < DD) ? Wih1[(size_t)hh * DD + gk + 0] : 0.f;
                    wv4.y = (gk + 1 < DD) ? Wih1[(size_t)hh * DD + gk + 1] : 0.f;
                    wv4.z = (gk + 2 < DD) ? Wih1[(size_t)hh * DD + gk + 2] : 0.f;
                    wv4.w = (gk + 3 < DD) ? Wih1[(size_t)hh * DD + gk + 3] : 0.f;
                }
                const unsigned lo = (unsigned)f2bf(wv4.x) | ((unsigned)f2bf(wv4.y) << 16);
                const unsigned hi = (unsigned)f2bf(wv4.z) | ((unsigned)f2bf(wv4.w) << 16);
                *(uint2*)&w_s[hh * WPIT + kk] = make_uint2(lo, hi);
            }
        }
        __syncthreads();                       // w_s ready

        if (mfw) {
            auto xissue = [&](int s, float4& da, float4& db) {
                const int gk = k0 + s * 32 + kg;
                if (gk + 7 < DD) {             // fast path (all but tail chunk)
                    da = *(const float4*)&xrow[gk];
                    db = *(const float4*)&xrow[gk + 4];
                } else {                       // guarded tail (k >= 1250 -> 0)
                    float tv[8];
                    #pragma unroll
                    for (int e = 0; e < 8; ++e)
                        tv[e] = (gk + e < DD) ? xrow[gk + e] : 0.f;
                    da = make_float4(tv[0], tv[1], tv[2], tv[3]);
                    db = make_float4(tv[4], tv[5], tv[6], tv[7]);
                }
            };
            xissue(0, xqa[0], xqb[0]);
            xissue(1, xqa[1], xqb[1]);
            #pragma unroll
            for (int s = 0; s < 8; ++s) {      // 8 k-steps of 32
                const int sl = s & 1;          // compile-time under unroll
                const float4 ua = xqa[sl], ub = xqb[sl];
                if (s + 2 < 8) xissue(s + 2, xqa[sl], xqb[sl]);
                const s16x8 af = {
                    (short)f2bf(ua.x), (short)f2bf(ua.y),
                    (short)f2bf(ua.z), (short)f2bf(ua.w),
                    (short)f2bf(ub.x), (short)f2bf(ub.y),
                    (short)f2bf(ub.z), (short)f2bf(ub.w) };
                #pragma unroll
                for (int nt = 0; nt < 7; ++nt) {
                    const s16x8 bf = *(const s16x8*)
                        &w_s[(nt * 16 + c16) * WPIT + s * 32 + kg];
                    acc[nt] = __builtin_amdgcn_mfma_f32_16x16x32_bf16(
                        af, bf, acc[nt], 0, 0, 0);
                }
            }
        }
    }

    __syncthreads();                           // all MFMA done; w_s now dead

    // C/D layout (m89-verified): col = l&15, row = (l>>4)*4 + reg
    if (mfw) {
        const int srow = wv * 16 + ((ln >> 4) << 2);
        #pragma unroll
        for (int nt = 0; nt < 7; ++nt) {
            const int col = nt * 16 + c16;
            if (col < H1) {
                #pragma unroll
                for (int r = 0; r < 4; ++r) {
                    const int row = srow + r;
                    if (row < TT) sp->pre1[row * H1 + col] = acc[nt][r];
                }
            }
        }
    }

    // ============== per-thread scan weights into registers ===================
    const int h = tid >> 1;
    const int p = tid & 1;
    const bool l1t = (tid < 200);
    float w1r[50]; float b1 = 0.f;
    if (l1t) {
        #pragma unroll
        for (int jq = 0; jq < 25; ++jq) {
            float2 v = *(const float2*)&Whh1[h * H1 + p * 50 + 2 * jq];
            w1r[2 * jq] = v.x; w1r[2 * jq + 1] = v.y;
        }
        if (p == 0) b1 = bih1[h] + bhh1[h];
    }
    const bool l2t = (tid >= 256 && tid < 256 + 4 * H2);
    const int k2 = (tid - 256) >> 2;
    const int p2 = (tid - 256) & 3;
    float wi2r[25], wh2r[5]; float b2 = 0.f;
    if (l2t) {
        #pragma unroll
        for (int j = 0; j < 25; ++j) wi2r[j] = Wih2[k2 * H1 + p2 * 25 + j];
        #pragma unroll
        for (int l = 0; l < 5; ++l)  wh2r[l] = Whh2[k2 * H2 + p2 * 5 + l];
        if (p2 == 0) b2 = bih2[k2] + bhh2[k2];
    }
    if (tid < H1) { sp->h1[0][tid] = 0.f; sp->h1[1][tid] = 0.f;
                    sp->o1[0][tid] = 0.f; sp->o1[1][tid] = 0.f; }
    if (tid < H2) { sp->h2[0][tid] = 0.f; sp->h2[1][tid] = 0.f; }

    const bool pm = l1t && (p == 1);
    const bool pp = l1t && (p == 0);
    float mreg[4], preg[4];
    #pragma unroll
    for (int u = 0; u < 4; ++u) if (pm) mreg[u] = m1b[u * H1 + h];

    __syncthreads();                           // pre1 + zeroed states visible

    #pragma unroll
    for (int u = 0; u < 4; ++u) if (pp) preg[u] = sp->pre1[u * H1 + h];

    // ================= Phase 2: fused two-layer scan =========================
    for (int tb = 0; tb < TT; tb += 4) {
        #pragma unroll
        for (int u = 0; u < 4; ++u) {
            const int t = tb + u;
            const int cur = t & 1, nxt = cur ^ 1;

            if (l1t) {
                float a0 = pp ? (preg[u] + b1) : 0.f;
                float a1 = 0.f, a2 = 0.f, a3 = 0.f;
                const float* hb = &sp->h1[cur][p * 50];
                #pragma unroll
                for (int jq = 0; jq < 12; ++jq) {
                    const float4 hv = *(const float4*)&hb[4 * jq];
                    a0 = fmaf(w1r[4 * jq + 0], hv.x, a0);
                    a1 = fmaf(w1r[4 * jq + 1], hv.y, a1);
                    a2 = fmaf(w1r[4 * jq + 2], hv.z, a2);
                    a3 = fmaf(w1r[4 * jq + 3], hv.w, a3);
                }
                const float2 ht = *(const float2*)&hb[48];
                a0 = fmaf(w1r[48], ht.x, a0);
                a1 = fmaf(w1r[49], ht.y, a1);
                float part = (a0 + a1) + (a2 + a3);
                float tot  = part + __shfl_xor(part, 1);
                tot = fmaxf(tot, 0.f);                       // h1(t)
                if (p == 0) sp->h1[nxt][h] = tot;
                else        sp->o1[nxt][h] = tot * mreg[u];
            }

            if (l2t && t >= 1) {
                float a0 = (p2 == 0) ? b2 : 0.f;
                float a1 = 0.f, a2 = 0.f, a3 = 0.f;
                const float* ob = &sp->o1[cur][p2 * 25];
                #pragma unroll
                for (int iq = 0; iq < 6; ++iq) {
                    const float4 ov = *(const float4*)&ob[4 * iq];
                    a0 = fmaf(wi2r[4 * iq + 0], ov.x, a0);
                    a1 = fmaf(wi2r[4 * iq + 1], ov.y, a1);
                    a2 = fmaf(wi2r[4 * iq + 2], ov.z, a2);
                    a3 = fmaf(wi2r[4 * iq + 3], ov.w, a3);
                }
                a0 = fmaf(wi2r[24], ob[24], a0);
                const float* gb = &sp->h2[cur][p2 * 5];
                #pragma unroll
                for (int l = 0; l < 5; ++l) a0 = fmaf(wh2r[l], gb[l], a0);
                float part = (a0 + a1) + (a2 + a3);
                part += __shfl_xor(part, 1);
                part += __shfl_xor(part, 2);
                const float h2v = fmaxf(part, 0.f);          // h2(t-1)
                if (p2 == 0) sp->h2[nxt][k2] = h2v;
            }

            if (t + 4 < TT) {
                if (pm) mreg[u] = m1b[(t + 4) * H1 + h];
                if (pp) preg[u] = sp->pre1[(t + 4) * H1 + h];
            }
            __syncthreads();
        }
    }

    // epilogue t = TT: layer2 computes h2(199)
    {
        const int cur = TT & 1;                              // 0
        if (l2t) {
            float a0 = (p2 == 0) ? b2 : 0.f;
            float a1 = 0.f, a2 = 0.f, a3 = 0.f;
            const float* ob = &sp->o1[cur][p2 * 25];
            #pragma unroll
            for (int iq = 0; iq < 6; ++iq) {
                const float4 ov = *(const float4*)&ob[4 * iq];
                a0 = fmaf(wi2r[4 * iq + 0], ov.x, a0);
                a1 = fmaf(wi2r[4 * iq + 1], ov.y, a1);
                a2 = fmaf(wi2r[4 * iq + 2], ov.z, a2);
                a3 = fmaf(wi2r[4 * iq + 3], ov.w, a3);
            }
            a0 = fmaf(wi2r[24], ob[24], a0);
            const float* gb = &sp->h2[cur][p2 * 5];
            #pragma unroll
            for (int l = 0; l < 5; ++l) a0 = fmaf(wh2r[l], gb[l], a0);
            float part = (a0 + a1) + (a2 + a3);
            part += __shfl_xor(part, 1);
            part += __shfl_xor(part, 2);
            if (p2 == 0) sp->h2f[k2] = fmaxf(part, 0.f);     // h2(199)
        }
        __syncthreads();
    }

    // ================= FC on last step ======================================
    if (tid < NO) {
        const float* m2 = mask2 + ((size_t)b * TT + (TT - 1)) * H2;
        float s = bfc[tid];
        #pragma unroll
        for (int k = 0; k < H2; ++k)
            s = fmaf(Wfc[tid * H2 + k], sp->h2f[k] * m2[k], s);
        out[b * NO + tid] = s;
    }
}

extern "C" void kernel_launch(void* const* d_in, const int* in_sizes, int n_in,
                              void* d_out, int out_size, void* d_ws, size_t ws_size,
                              hipStream_t stream) {
    rnn_fused<<<dim3(NB), dim3(1024), 0, stream>>>(
        (const float*)d_in[0],  (const float*)d_in[1],  (const float*)d_in[2],
        (const float*)d_in[3],  (const float*)d_in[4],  (const float*)d_in[5],
        (const float*)d_in[6],  (const float*)d_in[7],  (const float*)d_in[8],
        (const float*)d_in[9],  (const float*)d_in[10], (const float*)d_in[11],
        (const float*)d_in[12], (float*)d_out);
}